// Round 2
// baseline (1438.654 us; speedup 1.0000x reference)
//
#include <hip/hip_runtime.h>
#include <math.h>

// Problem constants (from reference): B=4, T=1024, C=1024, H=16, DH=64
namespace {
constexpr int NB  = 4;
constexpr int NT  = 1024;
constexpr int NC  = 1024;
constexpr int NH  = 16;
constexpr int NDH = 64;
constexpr int MT  = NB * NT;  // 4096 rows of x
}

// ---------------- elementwise tanh (vectorized float4) ----------------
__global__ __launch_bounds__(256) void k_tanh(const float* __restrict__ in,
                                              float* __restrict__ out, int n4) {
  int i = blockIdx.x * blockDim.x + threadIdx.x;
  if (i < n4) {
    float4 v = reinterpret_cast<const float4*>(in)[i];
    v.x = tanhf(v.x); v.y = tanhf(v.y); v.z = tanhf(v.z); v.w = tanhf(v.w);
    reinterpret_cast<float4*>(out)[i] = v;
  }
}

// ---------------- tiled M x N x D kernel ----------------
// OP==0: Out[m][n] = (0.5 - (1/1024)*sum_d |A[m][d]-B[n][d]|) * G[n]   (L1 proj)
// OP==1: Out[m][n] = sum_d A[m][d]*B[n][d] + G[n]                       (final GEMM)
// Tile: BM=BN=128, BD=32. 256 threads, 8x8 micro-tile per thread.
// LDS transposed [d][m] so micro-fragments read as ds_read_b128.
template <int OP>
__global__ __launch_bounds__(256) void k_mnd(const float* __restrict__ A,
                                             const float* __restrict__ Bmat,
                                             const float* __restrict__ g0,
                                             const float* __restrict__ g1,
                                             const float* __restrict__ g2,
                                             float* __restrict__ Out) {
  constexpr int BM = 128, BN = 128, BD = 32;
  __shared__ float As[BD][BM];
  __shared__ float Bs[BD][BN];

  const int tid = threadIdx.x;
  const int z = blockIdx.z;
  const float* Bz = Bmat + (size_t)z * NC * NC;
  const float* G = (z == 0) ? g0 : ((z == 1) ? g1 : g2);
  float* Oz = Out + (size_t)z * (size_t)MT * NC;
  const int m0 = blockIdx.y * BM;
  const int n0 = blockIdx.x * BN;
  const int ty = tid >> 4;   // 0..15 -> rows ty*8..ty*8+7
  const int tx = tid & 15;   // 0..15 -> cols tx*8..tx*8+7

  float acc[8][8];
#pragma unroll
  for (int i = 0; i < 8; ++i)
#pragma unroll
    for (int j = 0; j < 8; ++j) acc[i][j] = 0.0f;

  for (int d0 = 0; d0 < NC; d0 += BD) {
    // stage A-tile and B-tile transposed into LDS
#pragma unroll
    for (int i = 0; i < 4; ++i) {
      int idx = tid + i * 256;       // 0..1023
      int r = idx >> 3;              // 0..127
      int dq = (idx & 7) << 2;       // 0,4,...,28
      float4 av = *reinterpret_cast<const float4*>(A + (size_t)(m0 + r) * NC + d0 + dq);
      As[dq + 0][r] = av.x; As[dq + 1][r] = av.y;
      As[dq + 2][r] = av.z; As[dq + 3][r] = av.w;
      float4 bv = *reinterpret_cast<const float4*>(Bz + (size_t)(n0 + r) * NC + d0 + dq);
      Bs[dq + 0][r] = bv.x; Bs[dq + 1][r] = bv.y;
      Bs[dq + 2][r] = bv.z; Bs[dq + 3][r] = bv.w;
    }
    __syncthreads();

#pragma unroll 8
    for (int d = 0; d < BD; ++d) {
      float4 a0 = *reinterpret_cast<const float4*>(&As[d][ty * 8]);
      float4 a1 = *reinterpret_cast<const float4*>(&As[d][ty * 8 + 4]);
      float4 b0 = *reinterpret_cast<const float4*>(&Bs[d][tx * 8]);
      float4 b1 = *reinterpret_cast<const float4*>(&Bs[d][tx * 8 + 4]);
      float av[8] = {a0.x, a0.y, a0.z, a0.w, a1.x, a1.y, a1.z, a1.w};
      float bv[8] = {b0.x, b0.y, b0.z, b0.w, b1.x, b1.y, b1.z, b1.w};
#pragma unroll
      for (int i = 0; i < 8; ++i)
#pragma unroll
        for (int j = 0; j < 8; ++j) {
          if (OP == 0)
            acc[i][j] += fabsf(av[i] - bv[j]);
          else
            acc[i][j] = fmaf(av[i], bv[j], acc[i][j]);
        }
    }
    __syncthreads();
  }

  // epilogue
#pragma unroll
  for (int i = 0; i < 8; ++i) {
    int row = m0 + ty * 8 + i;
    float* orow = Oz + (size_t)row * NC + n0 + tx * 8;
    float vals[8];
#pragma unroll
    for (int j = 0; j < 8; ++j) {
      if (OP == 0)
        vals[j] = (0.5f - acc[i][j] * (1.0f / 1024.0f)) * G[n0 + tx * 8 + j];
      else
        vals[j] = acc[i][j] + G[n0 + tx * 8 + j];
    }
    float4 o0 = {vals[0], vals[1], vals[2], vals[3]};
    float4 o1 = {vals[4], vals[5], vals[6], vals[7]};
    *reinterpret_cast<float4*>(orow) = o0;
    *reinterpret_cast<float4*>(orow + 4) = o1;
  }
}

// ---------------- fused Student-t attention ----------------
// Block = one (b, h, 64-row q-tile). Streams over 16 k-tiles of 64 rows.
// dist[q][k] = (1/64) sum_d |q-k|; w = exp2(-r*log2(1+g*dist));
// out[q][d] = (sum_k w*v) / (sum_k w + 1e-6)
__global__ __launch_bounds__(256) void k_attn(const float* __restrict__ qb,
                                              const float* __restrict__ kb,
                                              const float* __restrict__ vb,
                                              const float* __restrict__ gamma,
                                              const float* __restrict__ rho,
                                              float* __restrict__ att) {
  const int qt = blockIdx.x;  // 0..15
  const int h  = blockIdx.y;  // 0..15
  const int b  = blockIdx.z;  // 0..3

  __shared__ float Qs[NDH][64];   // [d][qrow]
  __shared__ float Ks[NDH][64];   // [d][krow]
  __shared__ float Vs[64][NDH];   // [krow][d]
  __shared__ float Ws[64][68];    // [krow][qrow] (+pad)
  __shared__ float Red[64][17];
  __shared__ float Inv[64];

  const int tid = threadIdx.x;
  const int ty = tid >> 4;  // q-row group: rows ty*4..+3
  const int tx = tid & 15;  // k-col group / d group: cols tx*4..+3

  const float g  = log1pf(expf(gamma[h])) + 1e-4f;
  const float rr = log1pf(expf(rho[h])) + 1e-4f;

  // stage Q tile transposed
#pragma unroll
  for (int i = 0; i < 4; ++i) {
    int idx = tid + i * 256;      // 0..1023
    int r = idx >> 4;             // 0..63
    int dq = (idx & 15) << 2;     // 0..60
    const float* src = qb + ((size_t)(b * NT + qt * 64 + r)) * NC + h * NDH + dq;
    float4 v = *reinterpret_cast<const float4*>(src);
    Qs[dq + 0][r] = v.x; Qs[dq + 1][r] = v.y;
    Qs[dq + 2][r] = v.z; Qs[dq + 3][r] = v.w;
  }

  float oacc[4][4];
  float wsum[4];
#pragma unroll
  for (int i = 0; i < 4; ++i) {
    wsum[i] = 0.0f;
#pragma unroll
    for (int j = 0; j < 4; ++j) oacc[i][j] = 0.0f;
  }

  for (int kt = 0; kt < 16; ++kt) {
    __syncthreads();  // Q visible (iter 0); prev PV done (later iters)
    // stage K (transposed) and V (natural)
#pragma unroll
    for (int i = 0; i < 4; ++i) {
      int idx = tid + i * 256;
      int r = idx >> 4;
      int dq = (idx & 15) << 2;
      size_t rowoff = ((size_t)(b * NT + kt * 64 + r)) * NC + h * NDH + dq;
      float4 kv4 = *reinterpret_cast<const float4*>(kb + rowoff);
      Ks[dq + 0][r] = kv4.x; Ks[dq + 1][r] = kv4.y;
      Ks[dq + 2][r] = kv4.z; Ks[dq + 3][r] = kv4.w;
      *reinterpret_cast<float4*>(&Vs[r][dq]) =
          *reinterpret_cast<const float4*>(vb + rowoff);
    }
    __syncthreads();

    // L1 distances for 4x4 micro-tile
    float dl[4][4];
#pragma unroll
    for (int i = 0; i < 4; ++i)
#pragma unroll
      for (int j = 0; j < 4; ++j) dl[i][j] = 0.0f;

#pragma unroll 8
    for (int d = 0; d < NDH; ++d) {
      float4 qv = *reinterpret_cast<const float4*>(&Qs[d][ty * 4]);
      float4 kv = *reinterpret_cast<const float4*>(&Ks[d][tx * 4]);
      float qa[4] = {qv.x, qv.y, qv.z, qv.w};
      float ka[4] = {kv.x, kv.y, kv.z, kv.w};
#pragma unroll
      for (int i = 0; i < 4; ++i)
#pragma unroll
        for (int j = 0; j < 4; ++j) dl[i][j] += fabsf(qa[i] - ka[j]);
    }

    // Student-t weights
#pragma unroll
    for (int i = 0; i < 4; ++i)
#pragma unroll
      for (int j = 0; j < 4; ++j) {
        float dist = dl[i][j] * (1.0f / 64.0f);
        float w = exp2f(-rr * log2f(fmaf(g, dist, 1.0f)));
        wsum[i] += w;
        Ws[tx * 4 + j][ty * 4 + i] = w;
      }
    __syncthreads();

    // PV accumulate: oacc[i][j] over k of Ws[k][qrow]*Vs[k][d]
#pragma unroll 8
    for (int k = 0; k < 64; ++k) {
      float4 wv = *reinterpret_cast<const float4*>(&Ws[k][ty * 4]);
      float4 vv = *reinterpret_cast<const float4*>(&Vs[k][tx * 4]);
      float wa[4] = {wv.x, wv.y, wv.z, wv.w};
      float va[4] = {vv.x, vv.y, vv.z, vv.w};
#pragma unroll
      for (int i = 0; i < 4; ++i)
#pragma unroll
        for (int j = 0; j < 4; ++j) oacc[i][j] = fmaf(wa[i], va[j], oacc[i][j]);
    }
  }

  // row-sum reduction across the 16 tx groups
  __syncthreads();
#pragma unroll
  for (int i = 0; i < 4; ++i) Red[ty * 4 + i][tx] = wsum[i];
  __syncthreads();
  if (tid < 64) {
    float s = 0.0f;
#pragma unroll
    for (int x = 0; x < 16; ++x) s += Red[tid][x];
    Inv[tid] = 1.0f / (s + 1e-6f);
  }
  __syncthreads();

  // write out (att in [B,T,C] layout)
#pragma unroll
  for (int i = 0; i < 4; ++i) {
    int row = qt * 64 + ty * 4 + i;
    float inv = Inv[ty * 4 + i];
    float4 o = {oacc[i][0] * inv, oacc[i][1] * inv, oacc[i][2] * inv, oacc[i][3] * inv};
    float* dst = att + ((size_t)(b * NT + row)) * NC + h * NDH + tx * 4;
    *reinterpret_cast<float4*>(dst) = o;
  }
}

extern "C" void kernel_launch(void* const* d_in, const int* in_sizes, int n_in,
                              void* d_out, int out_size, void* d_ws, size_t ws_size,
                              hipStream_t stream) {
  (void)in_sizes; (void)n_in; (void)out_size; (void)ws_size;
  const float* x     = (const float*)d_in[0];
  const float* wq_w  = (const float*)d_in[1];
  const float* wq_g  = (const float*)d_in[2];
  const float* wk_w  = (const float*)d_in[3];
  const float* wk_g  = (const float*)d_in[4];
  const float* wv_w  = (const float*)d_in[5];
  const float* wv_g  = (const float*)d_in[6];
  const float* wo_w  = (const float*)d_in[7];
  const float* wo_b  = (const float*)d_in[8];
  const float* gamma = (const float*)d_in[9];
  const float* rho   = (const float*)d_in[10];
  float* out = (float*)d_out;

  // workspace layout (floats):
  float* xa  = (float*)d_ws;                       // 4096*1024
  float* wa  = xa + (size_t)MT * NC;               // 3 * 1024*1024
  float* qkv = wa + 3ull * NC * NC;                // 3 * 4096*1024
  float* att = qkv + 3ull * (size_t)MT * NC;       // 4096*1024
  float* qb = qkv;
  float* kb = qkv + (size_t)MT * NC;
  float* vb = qkv + 2ull * (size_t)MT * NC;

  // 1. tanh activations
  k_tanh<<<(MT * NC / 4) / 256, 256, 0, stream>>>(x, xa, MT * NC / 4);
  k_tanh<<<(NC * NC / 4) / 256, 256, 0, stream>>>(wq_w, wa, NC * NC / 4);
  k_tanh<<<(NC * NC / 4) / 256, 256, 0, stream>>>(wk_w, wa + (size_t)NC * NC, NC * NC / 4);
  k_tanh<<<(NC * NC / 4) / 256, 256, 0, stream>>>(wv_w, wa + 2ull * NC * NC, NC * NC / 4);

  // 2. q/k/v projections via L1 distance (z selects projection)
  k_mnd<0><<<dim3(NC / 128, MT / 128, 3), 256, 0, stream>>>(xa, wa, wq_g, wk_g, wv_g, qkv);

  // 3. fused Student-t attention
  k_attn<<<dim3(NT / 64, NH, NB), 256, 0, stream>>>(qb, kb, vb, gamma, rho, att);

  // 4. output projection GEMM
  k_mnd<1><<<dim3(NC / 128, MT / 128, 1), 256, 0, stream>>>(att, wo_w, wo_b, wo_b, wo_b, out);
}

// Round 3
// 834.184 us; speedup vs baseline: 1.7246x; 1.7246x over previous
//
#include <hip/hip_runtime.h>
#include <math.h>

// Problem constants: B=4, T=1024, C=1024, H=16, DH=64
namespace {
constexpr int NB  = 4;
constexpr int NT  = 1024;
constexpr int NC  = 1024;
constexpr int NH  = 16;
constexpr int NDH = 64;
constexpr int MT  = NB * NT;   // 4096
constexpr int KW  = NC / 2;    // 512 u32 (u16-pairs) per row
}

__device__ __forceinline__ unsigned sad16(unsigned a, unsigned b, unsigned c) {
#if __has_builtin(__builtin_amdgcn_sad_u16)
  return __builtin_amdgcn_sad_u16(a, b, c);
#else
  unsigned d;
  asm("v_sad_u16 %0, %1, %2, %3" : "=v"(d) : "v"(a), "v"(b), "v"(c));
  return d;
#endif
}

// ---------------- tanh + u16 quantize (8 floats -> 4 packed u32) ----------------
__global__ __launch_bounds__(256) void k_tanhq(const float* __restrict__ in,
                                               unsigned* __restrict__ out, int n8) {
  int i = blockIdx.x * blockDim.x + threadIdx.x;
  if (i >= n8) return;
  const float4* in4 = reinterpret_cast<const float4*>(in);
  float4 v0 = in4[2 * i], v1 = in4[2 * i + 1];
  float t[8] = {v0.x, v0.y, v0.z, v0.w, v1.x, v1.y, v1.z, v1.w};
  unsigned q[8];
#pragma unroll
  for (int j = 0; j < 8; ++j)
    q[j] = (unsigned)fmaf(tanhf(t[j]), 32767.0f, 32768.5f);  // (1, 65535]
  uint4 o = {q[0] | (q[1] << 16), q[2] | (q[3] << 16),
             q[4] | (q[5] << 16), q[6] | (q[7] << 16)};
  reinterpret_cast<uint4*>(out)[i] = o;
}

// ---------------- u16 SAD projection ----------------
// Out[z][m][n] = (0.5 - sad(Aq[m], Bq[z][n]) / (1024*32767)) * G[z][n]
// Tile 128x128, BD=32 u32 (64 dims). 256 threads, 8x8 u32 micro-tile,
// fragments split lo/hi (cols t*4 and 64+t*4) for conflict-free ds_read_b128.
__global__ __launch_bounds__(256) void k_sadproj(const unsigned* __restrict__ Aq,
                                                 const unsigned* __restrict__ Bq,
                                                 const float* __restrict__ g0,
                                                 const float* __restrict__ g1,
                                                 const float* __restrict__ g2,
                                                 float* __restrict__ Out) {
  constexpr int BD = 32;
  __shared__ unsigned As[BD][128];
  __shared__ unsigned Bs[BD][128];

  const int tid = threadIdx.x;
  const int z = blockIdx.z;
  const unsigned* Bz = Bq + (size_t)z * NC * KW;
  const float* G = (z == 0) ? g0 : ((z == 1) ? g1 : g2);
  float* Oz = Out + (size_t)z * (size_t)MT * NC;
  const int m0 = blockIdx.y * 128;
  const int n0 = blockIdx.x * 128;
  const int ty = tid >> 4;   // 0..15
  const int tx = tid & 15;   // 0..15

  unsigned acc[8][8];
#pragma unroll
  for (int i = 0; i < 8; ++i)
#pragma unroll
    for (int j = 0; j < 8; ++j) acc[i][j] = 0u;

  const int r_st = tid >> 3;        // 0..31
  const int c_st = (tid & 7) * 4;   // 0,4,...,28

  for (int s = 0; s < 16; ++s) {
    __syncthreads();
#pragma unroll
    for (int i = 0; i < 4; ++i) {
      int r = r_st + i * 32;  // 0..127
      uint4 av = *reinterpret_cast<const uint4*>(Aq + (size_t)(m0 + r) * KW + s * BD + c_st);
      As[c_st + 0][r] = av.x; As[c_st + 1][r] = av.y;
      As[c_st + 2][r] = av.z; As[c_st + 3][r] = av.w;
      uint4 bv = *reinterpret_cast<const uint4*>(Bz + (size_t)(n0 + r) * KW + s * BD + c_st);
      Bs[c_st + 0][r] = bv.x; Bs[c_st + 1][r] = bv.y;
      Bs[c_st + 2][r] = bv.z; Bs[c_st + 3][r] = bv.w;
    }
    __syncthreads();

#pragma unroll 2
    for (int d = 0; d < BD; ++d) {
      uint4 alo = *reinterpret_cast<const uint4*>(&As[d][ty * 4]);
      uint4 ahi = *reinterpret_cast<const uint4*>(&As[d][64 + ty * 4]);
      uint4 blo = *reinterpret_cast<const uint4*>(&Bs[d][tx * 4]);
      uint4 bhi = *reinterpret_cast<const uint4*>(&Bs[d][64 + tx * 4]);
      unsigned av[8] = {alo.x, alo.y, alo.z, alo.w, ahi.x, ahi.y, ahi.z, ahi.w};
      unsigned bv[8] = {blo.x, blo.y, blo.z, blo.w, bhi.x, bhi.y, bhi.z, bhi.w};
#pragma unroll
      for (int i = 0; i < 8; ++i)
#pragma unroll
        for (int j = 0; j < 8; ++j) acc[i][j] = sad16(av[i], bv[j], acc[i][j]);
    }
  }

  // epilogue: rows {ty*4+i, 64+ty*4+i}, cols {tx*4+j, 64+tx*4+j}
  const float invS = 1.0f / (1024.0f * 32767.0f);
  float gl[8];
#pragma unroll
  for (int j = 0; j < 4; ++j) {
    gl[j]     = G[n0 + tx * 4 + j];
    gl[j + 4] = G[n0 + 64 + tx * 4 + j];
  }
#pragma unroll
  for (int i = 0; i < 8; ++i) {
    int row = m0 + ((i < 4) ? (ty * 4 + i) : (64 + ty * 4 + (i - 4)));
    float* orow = Oz + (size_t)row * NC;
    float vals[8];
#pragma unroll
    for (int j = 0; j < 8; ++j)
      vals[j] = (0.5f - (float)acc[i][j] * invS) * gl[j];
    float4 o0 = {vals[0], vals[1], vals[2], vals[3]};
    float4 o1 = {vals[4], vals[5], vals[6], vals[7]};
    *reinterpret_cast<float4*>(orow + n0 + tx * 4) = o0;
    *reinterpret_cast<float4*>(orow + n0 + 64 + tx * 4) = o1;
  }
}

// ---------------- fp32 output GEMM: Out[m][n] = sum_d A[m][d]*B[n][d] + bias[n] ----------------
__global__ __launch_bounds__(256) void k_gemm(const float* __restrict__ A,
                                              const float* __restrict__ Bmat,
                                              const float* __restrict__ bias,
                                              float* __restrict__ Out) {
  constexpr int BM = 128, BN = 128, BD = 32;
  __shared__ float As[BD][BM];
  __shared__ float Bs[BD][BN];

  const int tid = threadIdx.x;
  const int m0 = blockIdx.y * BM;
  const int n0 = blockIdx.x * BN;
  const int ty = tid >> 4;
  const int tx = tid & 15;

  float acc[8][8];
#pragma unroll
  for (int i = 0; i < 8; ++i)
#pragma unroll
    for (int j = 0; j < 8; ++j) acc[i][j] = 0.0f;

  const int r_st = tid >> 3;       // 0..31 over 128 rows in 4 iters
  const int c_st = (tid & 7) * 4;

  for (int d0 = 0; d0 < NC; d0 += BD) {
    __syncthreads();
#pragma unroll
    for (int i = 0; i < 4; ++i) {
      int r = r_st + i * 32;
      float4 av = *reinterpret_cast<const float4*>(A + (size_t)(m0 + r) * NC + d0 + c_st);
      As[c_st + 0][r] = av.x; As[c_st + 1][r] = av.y;
      As[c_st + 2][r] = av.z; As[c_st + 3][r] = av.w;
      float4 bv = *reinterpret_cast<const float4*>(Bmat + (size_t)(n0 + r) * NC + d0 + c_st);
      Bs[c_st + 0][r] = bv.x; Bs[c_st + 1][r] = bv.y;
      Bs[c_st + 2][r] = bv.z; Bs[c_st + 3][r] = bv.w;
    }
    __syncthreads();

#pragma unroll 2
    for (int d = 0; d < BD; ++d) {
      float4 alo = *reinterpret_cast<const float4*>(&As[d][ty * 4]);
      float4 ahi = *reinterpret_cast<const float4*>(&As[d][64 + ty * 4]);
      float4 blo = *reinterpret_cast<const float4*>(&Bs[d][tx * 4]);
      float4 bhi = *reinterpret_cast<const float4*>(&Bs[d][64 + tx * 4]);
      float av[8] = {alo.x, alo.y, alo.z, alo.w, ahi.x, ahi.y, ahi.z, ahi.w};
      float bv[8] = {blo.x, blo.y, blo.z, blo.w, bhi.x, bhi.y, bhi.z, bhi.w};
#pragma unroll
      for (int i = 0; i < 8; ++i)
#pragma unroll
        for (int j = 0; j < 8; ++j) acc[i][j] = fmaf(av[i], bv[j], acc[i][j]);
    }
  }

  float bl[8];
#pragma unroll
  for (int j = 0; j < 4; ++j) {
    bl[j]     = bias[n0 + tx * 4 + j];
    bl[j + 4] = bias[n0 + 64 + tx * 4 + j];
  }
#pragma unroll
  for (int i = 0; i < 8; ++i) {
    int row = m0 + ((i < 4) ? (ty * 4 + i) : (64 + ty * 4 + (i - 4)));
    float* orow = Out + (size_t)row * NC;
    float4 o0 = {acc[i][0] + bl[0], acc[i][1] + bl[1], acc[i][2] + bl[2], acc[i][3] + bl[3]};
    float4 o1 = {acc[i][4] + bl[4], acc[i][5] + bl[5], acc[i][6] + bl[6], acc[i][7] + bl[7]};
    *reinterpret_cast<float4*>(orow + n0 + tx * 4) = o0;
    *reinterpret_cast<float4*>(orow + n0 + 64 + tx * 4) = o1;
  }
}

// ---------------- fused Student-t attention (fp32, unchanged) ----------------
__global__ __launch_bounds__(256) void k_attn(const float* __restrict__ qb,
                                              const float* __restrict__ kb,
                                              const float* __restrict__ vb,
                                              const float* __restrict__ gamma,
                                              const float* __restrict__ rho,
                                              float* __restrict__ att) {
  const int qt = blockIdx.x;
  const int h  = blockIdx.y;
  const int b  = blockIdx.z;

  __shared__ float Qs[NDH][64];
  __shared__ float Ks[NDH][64];
  __shared__ float Vs[64][NDH];
  __shared__ float Ws[64][68];
  __shared__ float Red[64][17];
  __shared__ float Inv[64];

  const int tid = threadIdx.x;
  const int ty = tid >> 4;
  const int tx = tid & 15;

  const float g  = log1pf(expf(gamma[h])) + 1e-4f;
  const float rr = log1pf(expf(rho[h])) + 1e-4f;

#pragma unroll
  for (int i = 0; i < 4; ++i) {
    int idx = tid + i * 256;
    int r = idx >> 4;
    int dq = (idx & 15) << 2;
    const float* src = qb + ((size_t)(b * NT + qt * 64 + r)) * NC + h * NDH + dq;
    float4 v = *reinterpret_cast<const float4*>(src);
    Qs[dq + 0][r] = v.x; Qs[dq + 1][r] = v.y;
    Qs[dq + 2][r] = v.z; Qs[dq + 3][r] = v.w;
  }

  float oacc[4][4];
  float wsum[4];
#pragma unroll
  for (int i = 0; i < 4; ++i) {
    wsum[i] = 0.0f;
#pragma unroll
    for (int j = 0; j < 4; ++j) oacc[i][j] = 0.0f;
  }

  for (int kt = 0; kt < 16; ++kt) {
    __syncthreads();
#pragma unroll
    for (int i = 0; i < 4; ++i) {
      int idx = tid + i * 256;
      int r = idx >> 4;
      int dq = (idx & 15) << 2;
      size_t rowoff = ((size_t)(b * NT + kt * 64 + r)) * NC + h * NDH + dq;
      float4 kv4 = *reinterpret_cast<const float4*>(kb + rowoff);
      Ks[dq + 0][r] = kv4.x; Ks[dq + 1][r] = kv4.y;
      Ks[dq + 2][r] = kv4.z; Ks[dq + 3][r] = kv4.w;
      *reinterpret_cast<float4*>(&Vs[r][dq]) =
          *reinterpret_cast<const float4*>(vb + rowoff);
    }
    __syncthreads();

    float dl[4][4];
#pragma unroll
    for (int i = 0; i < 4; ++i)
#pragma unroll
      for (int j = 0; j < 4; ++j) dl[i][j] = 0.0f;

#pragma unroll 8
    for (int d = 0; d < NDH; ++d) {
      float4 qv = *reinterpret_cast<const float4*>(&Qs[d][ty * 4]);
      float4 kv = *reinterpret_cast<const float4*>(&Ks[d][tx * 4]);
      float qa[4] = {qv.x, qv.y, qv.z, qv.w};
      float ka[4] = {kv.x, kv.y, kv.z, kv.w};
#pragma unroll
      for (int i = 0; i < 4; ++i)
#pragma unroll
        for (int j = 0; j < 4; ++j) dl[i][j] += fabsf(qa[i] - ka[j]);
    }

#pragma unroll
    for (int i = 0; i < 4; ++i)
#pragma unroll
      for (int j = 0; j < 4; ++j) {
        float dist = dl[i][j] * (1.0f / 64.0f);
        float w = exp2f(-rr * log2f(fmaf(g, dist, 1.0f)));
        wsum[i] += w;
        Ws[tx * 4 + j][ty * 4 + i] = w;
      }
    __syncthreads();

#pragma unroll 8
    for (int k = 0; k < 64; ++k) {
      float4 wv = *reinterpret_cast<const float4*>(&Ws[k][ty * 4]);
      float4 vv = *reinterpret_cast<const float4*>(&Vs[k][tx * 4]);
      float wa[4] = {wv.x, wv.y, wv.z, wv.w};
      float va[4] = {vv.x, vv.y, vv.z, vv.w};
#pragma unroll
      for (int i = 0; i < 4; ++i)
#pragma unroll
        for (int j = 0; j < 4; ++j) oacc[i][j] = fmaf(wa[i], va[j], oacc[i][j]);
    }
  }

  __syncthreads();
#pragma unroll
  for (int i = 0; i < 4; ++i) Red[ty * 4 + i][tx] = wsum[i];
  __syncthreads();
  if (tid < 64) {
    float s = 0.0f;
#pragma unroll
    for (int x = 0; x < 16; ++x) s += Red[tid][x];
    Inv[tid] = 1.0f / (s + 1e-6f);
  }
  __syncthreads();

#pragma unroll
  for (int i = 0; i < 4; ++i) {
    int row = qt * 64 + ty * 4 + i;
    float inv = Inv[ty * 4 + i];
    float4 o = {oacc[i][0] * inv, oacc[i][1] * inv, oacc[i][2] * inv, oacc[i][3] * inv};
    float* dst = att + ((size_t)(b * NT + row)) * NC + h * NDH + tx * 4;
    *reinterpret_cast<float4*>(dst) = o;
  }
}

extern "C" void kernel_launch(void* const* d_in, const int* in_sizes, int n_in,
                              void* d_out, int out_size, void* d_ws, size_t ws_size,
                              hipStream_t stream) {
  (void)in_sizes; (void)n_in; (void)out_size; (void)ws_size;
  const float* x     = (const float*)d_in[0];
  const float* wq_w  = (const float*)d_in[1];
  const float* wq_g  = (const float*)d_in[2];
  const float* wk_w  = (const float*)d_in[3];
  const float* wk_g  = (const float*)d_in[4];
  const float* wv_w  = (const float*)d_in[5];
  const float* wv_g  = (const float*)d_in[6];
  const float* wo_w  = (const float*)d_in[7];
  const float* wo_b  = (const float*)d_in[8];
  const float* gamma = (const float*)d_in[9];
  const float* rho   = (const float*)d_in[10];
  float* out = (float*)d_out;

  // workspace layout:
  unsigned* xq  = (unsigned*)d_ws;                    // 4096*512 u32
  unsigned* wqq = xq + (size_t)MT * KW;               // 3 * 1024*512 u32
  float* qkv = (float*)(wqq + 3ull * NC * KW);        // 3 * 4096*1024 f32
  float* att = qkv + 3ull * (size_t)MT * NC;          // 4096*1024 f32
  float* qb = qkv;
  float* kb = qkv + (size_t)MT * NC;
  float* vb = qkv + 2ull * (size_t)MT * NC;

  // 1. tanh + quantize to packed u16
  k_tanhq<<<(MT * NC / 8) / 256, 256, 0, stream>>>(x, xq, MT * NC / 8);
  k_tanhq<<<(NC * NC / 8) / 256, 256, 0, stream>>>(wq_w, wqq, NC * NC / 8);
  k_tanhq<<<(NC * NC / 8) / 256, 256, 0, stream>>>(wk_w, wqq + (size_t)NC * KW, NC * NC / 8);
  k_tanhq<<<(NC * NC / 8) / 256, 256, 0, stream>>>(wv_w, wqq + 2ull * NC * KW, NC * NC / 8);

  // 2. q/k/v projections via u16 SAD
  k_sadproj<<<dim3(NC / 128, MT / 128, 3), 256, 0, stream>>>(xq, wqq, wq_g, wk_g, wv_g, qkv);

  // 3. fused Student-t attention
  k_attn<<<dim3(NT / 64, NH, NB), 256, 0, stream>>>(qb, kb, vb, gamma, rho, att);

  // 4. output projection GEMM
  k_gemm<<<dim3(NC / 128, MT / 128, 1), 256, 0, stream>>>(att, wo_w, wo_b, out);
}

// Round 4
// 509.909 us; speedup vs baseline: 2.8214x; 1.6359x over previous
//
#include <hip/hip_runtime.h>
#include <math.h>

// Problem constants: B=4, T=1024, C=1024, H=16, DH=64
namespace {
constexpr int NB  = 4;
constexpr int NT  = 1024;
constexpr int NC  = 1024;
constexpr int NH  = 16;
constexpr int MT  = NB * NT;   // 4096
constexpr int KW  = NC / 2;    // 512 u32 (u16-pairs) per row
}

typedef _Float16 f16x8 __attribute__((ext_vector_type(8)));
typedef float f32x4 __attribute__((ext_vector_type(4)));

__device__ __forceinline__ unsigned sad16(unsigned a, unsigned b, unsigned c) {
#if __has_builtin(__builtin_amdgcn_sad_u16)
  return __builtin_amdgcn_sad_u16(a, b, c);
#else
  unsigned d;
  asm("v_sad_u16 %0, %1, %2, %3" : "=v"(d) : "v"(a), "v"(b), "v"(c));
  return d;
#endif
}

// quantize pair to u16 counts at 8192/unit, offset 32768 (for attention SAD)
__device__ __forceinline__ unsigned packq8k(float a, float b) {
  float fa = fminf(fmaxf(fmaf(a, 8192.0f, 32768.5f), 0.0f), 65535.0f);
  float fb = fminf(fmaxf(fmaf(b, 8192.0f, 32768.5f), 0.0f), 65535.0f);
  return (unsigned)fa | ((unsigned)fb << 16);
}

__device__ __forceinline__ unsigned short f16u(float x) {
  _Float16 h = (_Float16)x;
  return __builtin_bit_cast(unsigned short, h);
}

// ---------------- tanh + u16 quantize (8 floats -> 4 packed u32) ----------------
__global__ __launch_bounds__(256) void k_tanhq(const float* __restrict__ in,
                                               unsigned* __restrict__ out, int n8) {
  int i = blockIdx.x * blockDim.x + threadIdx.x;
  if (i >= n8) return;
  const float4* in4 = reinterpret_cast<const float4*>(in);
  float4 v0 = in4[2 * i], v1 = in4[2 * i + 1];
  float t[8] = {v0.x, v0.y, v0.z, v0.w, v1.x, v1.y, v1.z, v1.w};
  unsigned q[8];
#pragma unroll
  for (int j = 0; j < 8; ++j)
    q[j] = (unsigned)fmaf(tanhf(t[j]), 32767.0f, 32768.5f);
  uint4 o = {q[0] | (q[1] << 16), q[2] | (q[3] << 16),
             q[4] | (q[5] << 16), q[6] | (q[7] << 16)};
  reinterpret_cast<uint4*>(out)[i] = o;
}

// ---------------- u16 SAD projection ----------------
// val[m][n] = (0.5 - sad(Aq[m],Bq[z][n])/(1024*32767)) * G[n]
// z=0 -> qq_hm packed-u16 head-major [B*H][T][32 u32]
// z=1 -> kq_hm same layout
// z=2 -> vh_dm f16 d-major [B*H][64 d][T]
__global__ __launch_bounds__(256) void k_sadproj(const unsigned* __restrict__ Aq,
                                                 const unsigned* __restrict__ Bq,
                                                 const float* __restrict__ g0,
                                                 const float* __restrict__ g1,
                                                 const float* __restrict__ g2,
                                                 unsigned* __restrict__ qq_hm,
                                                 unsigned* __restrict__ kq_hm,
                                                 unsigned short* __restrict__ vh_dm) {
  constexpr int BD = 32;
  __shared__ unsigned As[BD][128];
  __shared__ unsigned Bs[BD][128];

  const int tid = threadIdx.x;
  const int z = blockIdx.z;
  const unsigned* Bz = Bq + (size_t)z * NC * KW;
  const float* G = (z == 0) ? g0 : ((z == 1) ? g1 : g2);
  const int m0 = blockIdx.y * 128;
  const int n0 = blockIdx.x * 128;
  const int ty = tid >> 4;
  const int tx = tid & 15;

  unsigned acc[8][8];
#pragma unroll
  for (int i = 0; i < 8; ++i)
#pragma unroll
    for (int j = 0; j < 8; ++j) acc[i][j] = 0u;

  const int r_st = tid >> 3;
  const int c_st = (tid & 7) * 4;

  for (int s = 0; s < 16; ++s) {
    __syncthreads();
#pragma unroll
    for (int i = 0; i < 4; ++i) {
      int r = r_st + i * 32;
      uint4 av = *reinterpret_cast<const uint4*>(Aq + (size_t)(m0 + r) * KW + s * BD + c_st);
      As[c_st + 0][r] = av.x; As[c_st + 1][r] = av.y;
      As[c_st + 2][r] = av.z; As[c_st + 3][r] = av.w;
      uint4 bv = *reinterpret_cast<const uint4*>(Bz + (size_t)(n0 + r) * KW + s * BD + c_st);
      Bs[c_st + 0][r] = bv.x; Bs[c_st + 1][r] = bv.y;
      Bs[c_st + 2][r] = bv.z; Bs[c_st + 3][r] = bv.w;
    }
    __syncthreads();

#pragma unroll 2
    for (int d = 0; d < BD; ++d) {
      uint4 alo = *reinterpret_cast<const uint4*>(&As[d][ty * 4]);
      uint4 ahi = *reinterpret_cast<const uint4*>(&As[d][64 + ty * 4]);
      uint4 blo = *reinterpret_cast<const uint4*>(&Bs[d][tx * 4]);
      uint4 bhi = *reinterpret_cast<const uint4*>(&Bs[d][64 + tx * 4]);
      unsigned av[8] = {alo.x, alo.y, alo.z, alo.w, ahi.x, ahi.y, ahi.z, ahi.w};
      unsigned bv[8] = {blo.x, blo.y, blo.z, blo.w, bhi.x, bhi.y, bhi.z, bhi.w};
#pragma unroll
      for (int i = 0; i < 8; ++i)
#pragma unroll
        for (int j = 0; j < 8; ++j) acc[i][j] = sad16(av[i], bv[j], acc[i][j]);
    }
  }

  const float invS = 1.0f / (1024.0f * 32767.0f);
  const int bI = m0 >> 10;         // batch
  const int tBase = m0 & 1023;     // t of tile row 0
  const int hl = n0 >> 6;          // head of lo col-group
  float gl[8];
#pragma unroll
  for (int j = 0; j < 4; ++j) {
    gl[j]     = G[n0 + tx * 4 + j];
    gl[j + 4] = G[n0 + 64 + tx * 4 + j];
  }

  if (z < 2) {
    unsigned* dst = (z == 0) ? qq_hm : kq_hm;
#pragma unroll
    for (int i = 0; i < 8; ++i) {
      int rr = (i < 4) ? (ty * 4 + i) : (64 + ty * 4 + (i - 4));
      int t = tBase + rr;
      float v[8];
#pragma unroll
      for (int j = 0; j < 8; ++j)
        v[j] = (0.5f - (float)acc[i][j] * invS) * gl[j];
      // lo head
      uint2 plo = {packq8k(v[0], v[1]), packq8k(v[2], v[3])};
      *reinterpret_cast<uint2*>(dst + (((size_t)(bI * NH + hl)) * NT + t) * 32 + tx * 2) = plo;
      // hi head
      uint2 phi = {packq8k(v[4], v[5]), packq8k(v[6], v[7])};
      *reinterpret_cast<uint2*>(dst + (((size_t)(bI * NH + hl + 1)) * NT + t) * 32 + tx * 2) = phi;
    }
  } else {
    // v: f16 d-major [bh][dh][t]; pack 4 consecutive t per store
#pragma unroll
    for (int j = 0; j < 8; ++j) {
      int h = hl + (j >> 2);
      int dh = tx * 4 + (j & 3);
      float gj = gl[j];
#pragma unroll
      for (int gI = 0; gI < 2; ++gI) {
        int t0 = tBase + gI * 64 + ty * 4;
        ushort4 o;
        o.x = f16u((0.5f - (float)acc[gI * 4 + 0][j] * invS) * gj);
        o.y = f16u((0.5f - (float)acc[gI * 4 + 1][j] * invS) * gj);
        o.z = f16u((0.5f - (float)acc[gI * 4 + 2][j] * invS) * gj);
        o.w = f16u((0.5f - (float)acc[gI * 4 + 3][j] * invS) * gj);
        *reinterpret_cast<ushort4*>(vh_dm + ((size_t)(bI * NH + h) * 64 + dh) * NT + t0) = o;
      }
    }
  }
}

// ---------------- fused Student-t attention: u16-SAD dist + f16 MFMA PV ----------------
__global__ __launch_bounds__(256, 4) void k_attn2(const unsigned* __restrict__ qq,
                                                  const unsigned* __restrict__ kq,
                                                  const unsigned short* __restrict__ vh,
                                                  const float* __restrict__ gamma,
                                                  const float* __restrict__ rho,
                                                  float* __restrict__ att) {
  const int qt = blockIdx.x;  // 0..15
  const int h  = blockIdx.y;  // 0..15
  const int b  = blockIdx.z;  // 0..3

  __shared__ unsigned Qs[32][68];  // [du32][qrow]
  __shared__ unsigned Ks[32][68];  // [du32][krow]
  __shared__ unsigned Ws[64][36];  // [qrow][kpair f16x2]
  __shared__ unsigned Vt[64][36];  // [d][kpair f16x2]

  const int tid = threadIdx.x;
  const int lane = tid & 63;
  const int wv = tid >> 6;   // wave 0..3 -> q rows wv*16..+15
  const int ty = tid >> 4;   // 0..15
  const int tx = tid & 15;   // 0..15

  const float g  = log1pf(expf(gamma[h])) + 1e-4f;
  const float rr = log1pf(expf(rho[h])) + 1e-4f;
  const float gs = g * (1.0f / (64.0f * 8192.0f));

  // stage Q once (8KB contiguous)
  const unsigned* qbase = qq + (((size_t)(b * NH + h)) * NT + qt * 64) * 32;
#pragma unroll
  for (int p = 0; p < 2; ++p) {
    int idx = tid + p * 256;      // 0..511
    int r = idx >> 3, c = idx & 7;
    uint4 v = *reinterpret_cast<const uint4*>(qbase + idx * 4);
    Qs[c * 4 + 0][r] = v.x; Qs[c * 4 + 1][r] = v.y;
    Qs[c * 4 + 2][r] = v.z; Qs[c * 4 + 3][r] = v.w;
  }

  f32x4 Cf[4] = {};            // 4 n-tiles of 16 d, C-frag per wave
  float wsum[4] = {0.f, 0.f, 0.f, 0.f};

  const unsigned* kbh = kq + (((size_t)(b * NH + h)) * NT) * 32;
  const unsigned short* vbh = vh + ((size_t)(b * NH + h) * 64) * NT;

  for (int kt = 0; kt < 16; ++kt) {
    __syncthreads();  // prev MFMA done reading Ks/Vt
    // stage K tile (transposed u32) and V tile (row-copy, d-major source)
    const unsigned* kbase = kbh + (size_t)(kt * 64) * 32;
#pragma unroll
    for (int p = 0; p < 2; ++p) {
      int idx = tid + p * 256;
      int r = idx >> 3, c = idx & 7;
      uint4 v = *reinterpret_cast<const uint4*>(kbase + idx * 4);
      Ks[c * 4 + 0][r] = v.x; Ks[c * 4 + 1][r] = v.y;
      Ks[c * 4 + 2][r] = v.z; Ks[c * 4 + 3][r] = v.w;
    }
    const unsigned short* vbase = vbh + kt * 64;
#pragma unroll
    for (int p = 0; p < 2; ++p) {
      int idx = tid + p * 256;
      int d = idx >> 3, tc = idx & 7;
      uint4 v = *reinterpret_cast<const uint4*>(vbase + (size_t)d * NT + tc * 8);
      *reinterpret_cast<uint4*>(&Vt[d][tc * 4]) = v;
    }
    __syncthreads();

    // SAD distances: 4 q-rows (ty) x 4 k-cols (tx)
    unsigned dl[4][4] = {};
#pragma unroll 8
    for (int d = 0; d < 32; ++d) {
      uint4 qv = *reinterpret_cast<const uint4*>(&Qs[d][ty * 4]);
      uint4 kv = *reinterpret_cast<const uint4*>(&Ks[d][tx * 4]);
      unsigned qa[4] = {qv.x, qv.y, qv.z, qv.w};
      unsigned ka[4] = {kv.x, kv.y, kv.z, kv.w};
#pragma unroll
      for (int i = 0; i < 4; ++i)
#pragma unroll
        for (int j = 0; j < 4; ++j) dl[i][j] = sad16(qa[i], ka[j], dl[i][j]);
    }

    // Student-t weights -> f16 pairs into Ws[q][k]
#pragma unroll
    for (int i = 0; i < 4; ++i) {
      float w0[4];
#pragma unroll
      for (int j = 0; j < 4; ++j) {
        float w = exp2f(-rr * log2f(fmaf(gs, (float)dl[i][j], 1.0f)));
        wsum[i] += w;
        w0[j] = w;
      }
      Ws[ty * 4 + i][tx * 2 + 0] = (unsigned)f16u(w0[0]) | ((unsigned)f16u(w0[1]) << 16);
      Ws[ty * 4 + i][tx * 2 + 1] = (unsigned)f16u(w0[2]) | ((unsigned)f16u(w0[3]) << 16);
    }
    __syncthreads();

    // PV: O[16q x 64d] += W^T V via 8 MFMA per wave
#pragma unroll
    for (int kk = 0; kk < 2; ++kk) {
      uint4 au = *reinterpret_cast<const uint4*>(&Ws[wv * 16 + (lane & 15)][(lane >> 4) * 4 + kk * 16]);
      f16x8 af = __builtin_bit_cast(f16x8, au);
#pragma unroll
      for (int nt = 0; nt < 4; ++nt) {
        uint4 bu = *reinterpret_cast<const uint4*>(&Vt[nt * 16 + (lane & 15)][(lane >> 4) * 4 + kk * 16]);
        f16x8 bf = __builtin_bit_cast(f16x8, bu);
        Cf[nt] = __builtin_amdgcn_mfma_f32_16x16x32_f16(af, bf, Cf[nt], 0, 0, 0);
      }
    }
  }

  // reduce wsum over the 16 tx lanes (within wave); result lands per (ty&3, i)
  float inv[4];
#pragma unroll
  for (int i = 0; i < 4; ++i) {
    float s = wsum[i];
    s += __shfl_xor(s, 1, 64);
    s += __shfl_xor(s, 2, 64);
    s += __shfl_xor(s, 4, 64);
    s += __shfl_xor(s, 8, 64);
    inv[i] = 1.0f / (s + 1e-6f);
  }

  // write: C row = (lane>>4)*4 + r matches inv[r]
  const size_t rowbase = (size_t)(b * NT + qt * 64 + wv * 16 + (lane >> 4) * 4);
  const int colbase = h * 64 + (lane & 15);
#pragma unroll
  for (int nt = 0; nt < 4; ++nt)
#pragma unroll
    for (int r = 0; r < 4; ++r)
      att[(rowbase + r) * NC + colbase + nt * 16] = Cf[nt][r] * inv[r];
}

// ---------------- fp32 output GEMM ----------------
__global__ __launch_bounds__(256) void k_gemm(const float* __restrict__ A,
                                              const float* __restrict__ Bmat,
                                              const float* __restrict__ bias,
                                              float* __restrict__ Out) {
  constexpr int BM = 128, BN = 128, BD = 32;
  __shared__ float As[BD][BM];
  __shared__ float Bs[BD][BN];

  const int tid = threadIdx.x;
  const int m0 = blockIdx.y * BM;
  const int n0 = blockIdx.x * BN;
  const int ty = tid >> 4;
  const int tx = tid & 15;

  float acc[8][8];
#pragma unroll
  for (int i = 0; i < 8; ++i)
#pragma unroll
    for (int j = 0; j < 8; ++j) acc[i][j] = 0.0f;

  const int r_st = tid >> 3;
  const int c_st = (tid & 7) * 4;

  for (int d0 = 0; d0 < NC; d0 += BD) {
    __syncthreads();
#pragma unroll
    for (int i = 0; i < 4; ++i) {
      int r = r_st + i * 32;
      float4 av = *reinterpret_cast<const float4*>(A + (size_t)(m0 + r) * NC + d0 + c_st);
      As[c_st + 0][r] = av.x; As[c_st + 1][r] = av.y;
      As[c_st + 2][r] = av.z; As[c_st + 3][r] = av.w;
      float4 bv = *reinterpret_cast<const float4*>(Bmat + (size_t)(n0 + r) * NC + d0 + c_st);
      Bs[c_st + 0][r] = bv.x; Bs[c_st + 1][r] = bv.y;
      Bs[c_st + 2][r] = bv.z; Bs[c_st + 3][r] = bv.w;
    }
    __syncthreads();

#pragma unroll 2
    for (int d = 0; d < BD; ++d) {
      float4 alo = *reinterpret_cast<const float4*>(&As[d][ty * 4]);
      float4 ahi = *reinterpret_cast<const float4*>(&As[d][64 + ty * 4]);
      float4 blo = *reinterpret_cast<const float4*>(&Bs[d][tx * 4]);
      float4 bhi = *reinterpret_cast<const float4*>(&Bs[d][64 + tx * 4]);
      float av[8] = {alo.x, alo.y, alo.z, alo.w, ahi.x, ahi.y, ahi.z, ahi.w};
      float bv[8] = {blo.x, blo.y, blo.z, blo.w, bhi.x, bhi.y, bhi.z, bhi.w};
#pragma unroll
      for (int i = 0; i < 8; ++i)
#pragma unroll
        for (int j = 0; j < 8; ++j) acc[i][j] = fmaf(av[i], bv[j], acc[i][j]);
    }
  }

  float bl[8];
#pragma unroll
  for (int j = 0; j < 4; ++j) {
    bl[j]     = bias[n0 + tx * 4 + j];
    bl[j + 4] = bias[n0 + 64 + tx * 4 + j];
  }
#pragma unroll
  for (int i = 0; i < 8; ++i) {
    int row = m0 + ((i < 4) ? (ty * 4 + i) : (64 + ty * 4 + (i - 4)));
    float* orow = Out + (size_t)row * NC;
    float4 o0 = {acc[i][0] + bl[0], acc[i][1] + bl[1], acc[i][2] + bl[2], acc[i][3] + bl[3]};
    float4 o1 = {acc[i][4] + bl[4], acc[i][5] + bl[5], acc[i][6] + bl[6], acc[i][7] + bl[7]};
    *reinterpret_cast<float4*>(orow + n0 + tx * 4) = o0;
    *reinterpret_cast<float4*>(orow + n0 + 64 + tx * 4) = o1;
  }
}

extern "C" void kernel_launch(void* const* d_in, const int* in_sizes, int n_in,
                              void* d_out, int out_size, void* d_ws, size_t ws_size,
                              hipStream_t stream) {
  (void)in_sizes; (void)n_in; (void)out_size; (void)ws_size;
  const float* x     = (const float*)d_in[0];
  const float* wq_w  = (const float*)d_in[1];
  const float* wq_g  = (const float*)d_in[2];
  const float* wk_w  = (const float*)d_in[3];
  const float* wk_g  = (const float*)d_in[4];
  const float* wv_w  = (const float*)d_in[5];
  const float* wv_g  = (const float*)d_in[6];
  const float* wo_w  = (const float*)d_in[7];
  const float* wo_b  = (const float*)d_in[8];
  const float* gamma = (const float*)d_in[9];
  const float* rho   = (const float*)d_in[10];
  float* out = (float*)d_out;

  // workspace layout:
  unsigned* xq   = (unsigned*)d_ws;                          // 4096*512 u32   (8MB)
  unsigned* wqq  = xq + (size_t)MT * KW;                     // 3*1024*512 u32 (6MB)
  unsigned* qqhm = wqq + 3ull * NC * KW;                     // 64*1024*32 u32 (8MB)
  unsigned* kqhm = qqhm + (size_t)NB * NH * NT * 32;         // 8MB
  unsigned short* vhdm = (unsigned short*)(kqhm + (size_t)NB * NH * NT * 32);  // 64*64*1024 f16 (8MB)
  float* att = (float*)(vhdm + (size_t)NB * NH * 64 * NT);   // 4096*1024 f32 (16MB)

  // 1. tanh + quantize
  k_tanhq<<<(MT * NC / 8) / 256, 256, 0, stream>>>(x, xq, MT * NC / 8);
  k_tanhq<<<(NC * NC / 8) / 256, 256, 0, stream>>>(wq_w, wqq, NC * NC / 8);
  k_tanhq<<<(NC * NC / 8) / 256, 256, 0, stream>>>(wk_w, wqq + (size_t)NC * KW, NC * NC / 8);
  k_tanhq<<<(NC * NC / 8) / 256, 256, 0, stream>>>(wv_w, wqq + 2ull * NC * KW, NC * NC / 8);

  // 2. q/k/v projections via u16 SAD, emitting attention-ready layouts
  k_sadproj<<<dim3(NC / 128, MT / 128, 3), 256, 0, stream>>>(xq, wqq, wq_g, wk_g, wv_g,
                                                             qqhm, kqhm, vhdm);

  // 3. fused Student-t attention (SAD dist + f16 MFMA PV)
  k_attn2<<<dim3(NT / 64, NH, NB), 256, 0, stream>>>(qqhm, kqhm, vhdm, gamma, rho, att);

  // 4. output projection GEMM
  k_gemm<<<dim3(NC / 128, MT / 128, 1), 256, 0, stream>>>(att, wo_w, wo_b, out);
}

// Round 5
// 264.084 us; speedup vs baseline: 5.4477x; 1.9309x over previous
//
#include <hip/hip_runtime.h>
#include <math.h>

// Problem constants: B=4, T=1024, C=1024, H=16, DH=64
namespace {
constexpr int NB  = 4;
constexpr int NT  = 1024;
constexpr int NC  = 1024;
constexpr int NH  = 16;
constexpr int MT  = NB * NT;   // 4096
constexpr int KW8 = NC / 4;    // 256 u32 (u8 x4) per row
}

typedef _Float16 f16x8 __attribute__((ext_vector_type(8)));
typedef float f32x4 __attribute__((ext_vector_type(4)));

__device__ __forceinline__ unsigned sad8(unsigned a, unsigned b, unsigned c) {
  unsigned d;
  asm("v_sad_u8 %0, %1, %2, %3" : "=v"(d) : "v"(a), "v"(b), "v"(c));
  return d;
}

__device__ __forceinline__ unsigned sad16(unsigned a, unsigned b, unsigned c) {
#if __has_builtin(__builtin_amdgcn_sad_u16)
  return __builtin_amdgcn_sad_u16(a, b, c);
#else
  unsigned d;
  asm("v_sad_u16 %0, %1, %2, %3" : "=v"(d) : "v"(a), "v"(b), "v"(c));
  return d;
#endif
}

// quantize pair to u16 counts at 8192/unit, offset 32768 (for attention SAD)
__device__ __forceinline__ unsigned packq8k(float a, float b) {
  float fa = fminf(fmaxf(fmaf(a, 8192.0f, 32768.5f), 0.0f), 65535.0f);
  float fb = fminf(fmaxf(fmaf(b, 8192.0f, 32768.5f), 0.0f), 65535.0f);
  return (unsigned)fa | ((unsigned)fb << 16);
}

__device__ __forceinline__ unsigned short f16u(float x) {
  _Float16 h = (_Float16)x;
  return __builtin_bit_cast(unsigned short, h);
}

// ---------------- tanh + u8 quantize (8 floats -> 2 packed u32) ----------------
__global__ __launch_bounds__(256) void k_tanhq8(const float* __restrict__ in,
                                                unsigned* __restrict__ out, int n8) {
  int i = blockIdx.x * blockDim.x + threadIdx.x;
  if (i >= n8) return;
  const float4* in4 = reinterpret_cast<const float4*>(in);
  float4 v0 = in4[2 * i], v1 = in4[2 * i + 1];
  float t[8] = {v0.x, v0.y, v0.z, v0.w, v1.x, v1.y, v1.z, v1.w};
  unsigned q[8];
#pragma unroll
  for (int j = 0; j < 8; ++j)
    q[j] = (unsigned)fmaf(tanhf(t[j]), 127.5f, 128.0f);  // 0..255
  uint2 o = {q[0] | (q[1] << 8) | (q[2] << 16) | (q[3] << 24),
             q[4] | (q[5] << 8) | (q[6] << 16) | (q[7] << 24)};
  reinterpret_cast<uint2*>(out)[i] = o;
}

// ---------------- fp32 -> f16 convert ----------------
__global__ __launch_bounds__(256) void k_cvt16(const float* __restrict__ in,
                                               unsigned short* __restrict__ out, int n8) {
  int i = blockIdx.x * blockDim.x + threadIdx.x;
  if (i >= n8) return;
  const float4* in4 = reinterpret_cast<const float4*>(in);
  float4 v0 = in4[2 * i], v1 = in4[2 * i + 1];
  ushort4 o0 = {f16u(v0.x), f16u(v0.y), f16u(v0.z), f16u(v0.w)};
  ushort4 o1 = {f16u(v1.x), f16u(v1.y), f16u(v1.z), f16u(v1.w)};
  reinterpret_cast<ushort4*>(out)[2 * i] = o0;
  reinterpret_cast<ushort4*>(out)[2 * i + 1] = o1;
}

// ---------------- u8 SAD projection ----------------
// val[m][n] = (0.5 - sad8(Aq[m],Bq[z][n])/(1024*127.5)) * G[n]
// z=0 -> qq_hm packed-u16 head-major [B*H][T][32 u32]
// z=1 -> kq_hm same layout
// z=2 -> vh_dm f16 d-major [B*H][64 d][T]
// LDS: transposed at u32 granularity, As[du][row], stride 132 (pad) conflict-free.
// Staging: in-register 4x4 transpose -> ds_write_b128 (threads<128: A, >=128: B).
__global__ __launch_bounds__(256) void k_sadproj8(const unsigned* __restrict__ Aq,
                                                  const unsigned* __restrict__ Bq,
                                                  const float* __restrict__ g0,
                                                  const float* __restrict__ g1,
                                                  const float* __restrict__ g2,
                                                  unsigned* __restrict__ qq_hm,
                                                  unsigned* __restrict__ kq_hm,
                                                  unsigned short* __restrict__ vh_dm) {
  __shared__ unsigned As[16][132];
  __shared__ unsigned Bs[16][132];

  const int tid = threadIdx.x;
  const int z = blockIdx.z;
  const unsigned* Bz = Bq + (size_t)z * NC * KW8;
  const float* G = (z == 0) ? g0 : ((z == 1) ? g1 : g2);
  const int m0 = blockIdx.y * 128;
  const int n0 = blockIdx.x * 128;
  const int ty = tid >> 4;   // 0..15
  const int tx = tid & 15;   // 0..15

  unsigned acc[8][8];
#pragma unroll
  for (int i = 0; i < 8; ++i)
#pragma unroll
    for (int j = 0; j < 8; ++j) acc[i][j] = 0u;

  const int tt = tid & 127;
  const int duq = tt & 3;          // uint4 column within chunk
  const int r0 = (tt >> 2) * 4;    // 0,4,...,124
  const bool doB = (tid >= 128);
  const unsigned* Src = doB ? (Bz + (size_t)n0 * KW8) : (Aq + (size_t)m0 * KW8);

  for (int s = 0; s < 16; ++s) {
    __syncthreads();
    // stage: 4 rows x uint4 -> register transpose -> 4 x ds_write_b128
    uint4 rv[4];
#pragma unroll
    for (int k2 = 0; k2 < 4; ++k2)
      rv[k2] = *reinterpret_cast<const uint4*>(Src + (size_t)(r0 + k2) * KW8 + s * 16 + duq * 4);
    uint4 w0 = {rv[0].x, rv[1].x, rv[2].x, rv[3].x};
    uint4 w1 = {rv[0].y, rv[1].y, rv[2].y, rv[3].y};
    uint4 w2 = {rv[0].z, rv[1].z, rv[2].z, rv[3].z};
    uint4 w3 = {rv[0].w, rv[1].w, rv[2].w, rv[3].w};
    if (doB) {
      *reinterpret_cast<uint4*>(&Bs[duq * 4 + 0][r0]) = w0;
      *reinterpret_cast<uint4*>(&Bs[duq * 4 + 1][r0]) = w1;
      *reinterpret_cast<uint4*>(&Bs[duq * 4 + 2][r0]) = w2;
      *reinterpret_cast<uint4*>(&Bs[duq * 4 + 3][r0]) = w3;
    } else {
      *reinterpret_cast<uint4*>(&As[duq * 4 + 0][r0]) = w0;
      *reinterpret_cast<uint4*>(&As[duq * 4 + 1][r0]) = w1;
      *reinterpret_cast<uint4*>(&As[duq * 4 + 2][r0]) = w2;
      *reinterpret_cast<uint4*>(&As[duq * 4 + 3][r0]) = w3;
    }
    __syncthreads();

#pragma unroll 4
    for (int du = 0; du < 16; ++du) {
      uint4 alo = *reinterpret_cast<const uint4*>(&As[du][ty * 4]);
      uint4 ahi = *reinterpret_cast<const uint4*>(&As[du][64 + ty * 4]);
      uint4 blo = *reinterpret_cast<const uint4*>(&Bs[du][tx * 4]);
      uint4 bhi = *reinterpret_cast<const uint4*>(&Bs[du][64 + tx * 4]);
      unsigned av[8] = {alo.x, alo.y, alo.z, alo.w, ahi.x, ahi.y, ahi.z, ahi.w};
      unsigned bv[8] = {blo.x, blo.y, blo.z, blo.w, bhi.x, bhi.y, bhi.z, bhi.w};
#pragma unroll
      for (int i = 0; i < 8; ++i)
#pragma unroll
        for (int j = 0; j < 8; ++j) acc[i][j] = sad8(av[i], bv[j], acc[i][j]);
    }
  }

  const float invS = 1.0f / (1024.0f * 127.5f);
  const int bI = m0 >> 10;
  const int tBase = m0 & 1023;
  const int hl = n0 >> 6;
  float gl[8];
#pragma unroll
  for (int j = 0; j < 4; ++j) {
    gl[j]     = G[n0 + tx * 4 + j];
    gl[j + 4] = G[n0 + 64 + tx * 4 + j];
  }

  if (z < 2) {
    unsigned* dst = (z == 0) ? qq_hm : kq_hm;
#pragma unroll
    for (int i = 0; i < 8; ++i) {
      int rr = (i < 4) ? (ty * 4 + i) : (64 + ty * 4 + (i - 4));
      int t = tBase + rr;
      float v[8];
#pragma unroll
      for (int j = 0; j < 8; ++j)
        v[j] = (0.5f - (float)acc[i][j] * invS) * gl[j];
      uint2 plo = {packq8k(v[0], v[1]), packq8k(v[2], v[3])};
      *reinterpret_cast<uint2*>(dst + (((size_t)(bI * NH + hl)) * NT + t) * 32 + tx * 2) = plo;
      uint2 phi = {packq8k(v[4], v[5]), packq8k(v[6], v[7])};
      *reinterpret_cast<uint2*>(dst + (((size_t)(bI * NH + hl + 1)) * NT + t) * 32 + tx * 2) = phi;
    }
  } else {
#pragma unroll
    for (int j = 0; j < 8; ++j) {
      int h = hl + (j >> 2);
      int dh = tx * 4 + (j & 3);
      float gj = gl[j];
#pragma unroll
      for (int gI = 0; gI < 2; ++gI) {
        int t0 = tBase + gI * 64 + ty * 4;
        ushort4 o;
        o.x = f16u((0.5f - (float)acc[gI * 4 + 0][j] * invS) * gj);
        o.y = f16u((0.5f - (float)acc[gI * 4 + 1][j] * invS) * gj);
        o.z = f16u((0.5f - (float)acc[gI * 4 + 2][j] * invS) * gj);
        o.w = f16u((0.5f - (float)acc[gI * 4 + 3][j] * invS) * gj);
        *reinterpret_cast<ushort4*>(vh_dm + ((size_t)(bI * NH + h) * 64 + dh) * NT + t0) = o;
      }
    }
  }
}

// ---------------- fused Student-t attention: u16-SAD dist + f16 MFMA PV ----------------
__global__ __launch_bounds__(256, 4) void k_attn2(const unsigned* __restrict__ qq,
                                                  const unsigned* __restrict__ kq,
                                                  const unsigned short* __restrict__ vh,
                                                  const float* __restrict__ gamma,
                                                  const float* __restrict__ rho,
                                                  unsigned short* __restrict__ att_h) {
  const int qt = blockIdx.x;
  const int h  = blockIdx.y;
  const int b  = blockIdx.z;

  __shared__ unsigned Qs[32][68];
  __shared__ unsigned Ks[32][68];
  __shared__ unsigned Ws[64][36];
  __shared__ unsigned Vt[64][36];

  const int tid = threadIdx.x;
  const int lane = tid & 63;
  const int wv = tid >> 6;
  const int ty = tid >> 4;
  const int tx = tid & 15;

  const float g  = log1pf(expf(gamma[h])) + 1e-4f;
  const float rr = log1pf(expf(rho[h])) + 1e-4f;
  const float gs = g * (1.0f / (64.0f * 8192.0f));

  const unsigned* qbase = qq + (((size_t)(b * NH + h)) * NT + qt * 64) * 32;
#pragma unroll
  for (int p = 0; p < 2; ++p) {
    int idx = tid + p * 256;
    int r = idx >> 3, c = idx & 7;
    uint4 v = *reinterpret_cast<const uint4*>(qbase + idx * 4);
    Qs[c * 4 + 0][r] = v.x; Qs[c * 4 + 1][r] = v.y;
    Qs[c * 4 + 2][r] = v.z; Qs[c * 4 + 3][r] = v.w;
  }

  f32x4 Cf[4] = {};
  float wsum[4] = {0.f, 0.f, 0.f, 0.f};

  const unsigned* kbh = kq + (((size_t)(b * NH + h)) * NT) * 32;
  const unsigned short* vbh = vh + ((size_t)(b * NH + h) * 64) * NT;

  for (int kt = 0; kt < 16; ++kt) {
    __syncthreads();
    const unsigned* kbase = kbh + (size_t)(kt * 64) * 32;
#pragma unroll
    for (int p = 0; p < 2; ++p) {
      int idx = tid + p * 256;
      int r = idx >> 3, c = idx & 7;
      uint4 v = *reinterpret_cast<const uint4*>(kbase + idx * 4);
      Ks[c * 4 + 0][r] = v.x; Ks[c * 4 + 1][r] = v.y;
      Ks[c * 4 + 2][r] = v.z; Ks[c * 4 + 3][r] = v.w;
    }
    const unsigned short* vbase = vbh + kt * 64;
#pragma unroll
    for (int p = 0; p < 2; ++p) {
      int idx = tid + p * 256;
      int d = idx >> 3, tc = idx & 7;
      uint4 v = *reinterpret_cast<const uint4*>(vbase + (size_t)d * NT + tc * 8);
      *reinterpret_cast<uint4*>(&Vt[d][tc * 4]) = v;
    }
    __syncthreads();

    unsigned dl[4][4] = {};
#pragma unroll 8
    for (int d = 0; d < 32; ++d) {
      uint4 qv = *reinterpret_cast<const uint4*>(&Qs[d][ty * 4]);
      uint4 kv = *reinterpret_cast<const uint4*>(&Ks[d][tx * 4]);
      unsigned qa[4] = {qv.x, qv.y, qv.z, qv.w};
      unsigned ka[4] = {kv.x, kv.y, kv.z, kv.w};
#pragma unroll
      for (int i = 0; i < 4; ++i)
#pragma unroll
        for (int j = 0; j < 4; ++j) dl[i][j] = sad16(qa[i], ka[j], dl[i][j]);
    }

#pragma unroll
    for (int i = 0; i < 4; ++i) {
      float w0[4];
#pragma unroll
      for (int j = 0; j < 4; ++j) {
        float w = exp2f(-rr * log2f(fmaf(gs, (float)dl[i][j], 1.0f)));
        wsum[i] += w;
        w0[j] = w;
      }
      Ws[ty * 4 + i][tx * 2 + 0] = (unsigned)f16u(w0[0]) | ((unsigned)f16u(w0[1]) << 16);
      Ws[ty * 4 + i][tx * 2 + 1] = (unsigned)f16u(w0[2]) | ((unsigned)f16u(w0[3]) << 16);
    }
    __syncthreads();

#pragma unroll
    for (int kk = 0; kk < 2; ++kk) {
      uint4 au = *reinterpret_cast<const uint4*>(&Ws[wv * 16 + (lane & 15)][(lane >> 4) * 4 + kk * 16]);
      f16x8 af = __builtin_bit_cast(f16x8, au);
#pragma unroll
      for (int nt = 0; nt < 4; ++nt) {
        uint4 bu = *reinterpret_cast<const uint4*>(&Vt[nt * 16 + (lane & 15)][(lane >> 4) * 4 + kk * 16]);
        f16x8 bf = __builtin_bit_cast(f16x8, bu);
        Cf[nt] = __builtin_amdgcn_mfma_f32_16x16x32_f16(af, bf, Cf[nt], 0, 0, 0);
      }
    }
  }

  float inv[4];
#pragma unroll
  for (int i = 0; i < 4; ++i) {
    float s = wsum[i];
    s += __shfl_xor(s, 1, 64);
    s += __shfl_xor(s, 2, 64);
    s += __shfl_xor(s, 4, 64);
    s += __shfl_xor(s, 8, 64);
    inv[i] = 1.0f / (s + 1e-6f);
  }

  const size_t rowbase = (size_t)(b * NT + qt * 64 + wv * 16 + (lane >> 4) * 4);
  const int colbase = h * 64 + (lane & 15);
#pragma unroll
  for (int nt = 0; nt < 4; ++nt)
#pragma unroll
    for (int r = 0; r < 4; ++r)
      att_h[(rowbase + r) * NC + colbase + nt * 16] = f16u(Cf[nt][r] * inv[r]);
}

// ---------------- f16 MFMA output GEMM: Out = A · Bw^T + bias ----------------
// A [4096][1024] f16, Bw [1024][1024] f16 (row = n), Out fp32.
__global__ __launch_bounds__(256) void k_gemm16(const unsigned short* __restrict__ A,
                                                const unsigned short* __restrict__ Bw,
                                                const float* __restrict__ bias,
                                                float* __restrict__ Out) {
  __shared__ unsigned Ash[128 * 20];  // row stride 20 u32 (40 f16, 80B)
  __shared__ unsigned Bsh[128 * 20];

  const int tid = threadIdx.x;
  const int m0 = blockIdx.y * 128;
  const int n0 = blockIdx.x * 128;
  const int lane = tid & 63;
  const int wv = tid >> 6;
  const int wr = wv >> 1, wc = wv & 1;
  const int lr = lane & 15, lq = lane >> 4;

  f32x4 acc[4][4] = {};

  const unsigned* A32 = reinterpret_cast<const unsigned*>(A);
  const unsigned* B32 = reinterpret_cast<const unsigned*>(Bw);

  for (int ks = 0; ks < 32; ++ks) {
    __syncthreads();
#pragma unroll
    for (int p = 0; p < 2; ++p) {
      int idx = tid + p * 256;
      int r = idx >> 2, q = idx & 3;
      uint4 av = *reinterpret_cast<const uint4*>(A32 + (size_t)(m0 + r) * 512 + ks * 16 + q * 4);
      *reinterpret_cast<uint4*>(&Ash[r * 20 + q * 4]) = av;
      uint4 bv = *reinterpret_cast<const uint4*>(B32 + (size_t)(n0 + r) * 512 + ks * 16 + q * 4);
      *reinterpret_cast<uint4*>(&Bsh[r * 20 + q * 4]) = bv;
    }
    __syncthreads();

    f16x8 af[4], bf[4];
#pragma unroll
    for (int f = 0; f < 4; ++f) {
      uint4 au = *reinterpret_cast<const uint4*>(&Ash[(wr * 64 + f * 16 + lr) * 20 + lq * 4]);
      af[f] = __builtin_bit_cast(f16x8, au);
      uint4 bu = *reinterpret_cast<const uint4*>(&Bsh[(wc * 64 + f * 16 + lr) * 20 + lq * 4]);
      bf[f] = __builtin_bit_cast(f16x8, bu);
    }
#pragma unroll
    for (int fm = 0; fm < 4; ++fm)
#pragma unroll
      for (int fn = 0; fn < 4; ++fn)
        acc[fm][fn] = __builtin_amdgcn_mfma_f32_16x16x32_f16(af[fm], bf[fn], acc[fm][fn], 0, 0, 0);
  }

#pragma unroll
  for (int fn = 0; fn < 4; ++fn) {
    int col = n0 + wc * 64 + fn * 16 + lr;
    float bb = bias[col];
#pragma unroll
    for (int fm = 0; fm < 4; ++fm) {
      int rowb = m0 + wr * 64 + fm * 16 + lq * 4;
#pragma unroll
      for (int r = 0; r < 4; ++r)
        Out[(size_t)(rowb + r) * NC + col] = acc[fm][fn][r] + bb;
    }
  }
}

extern "C" void kernel_launch(void* const* d_in, const int* in_sizes, int n_in,
                              void* d_out, int out_size, void* d_ws, size_t ws_size,
                              hipStream_t stream) {
  (void)in_sizes; (void)n_in; (void)out_size; (void)ws_size;
  const float* x     = (const float*)d_in[0];
  const float* wq_w  = (const float*)d_in[1];
  const float* wq_g  = (const float*)d_in[2];
  const float* wk_w  = (const float*)d_in[3];
  const float* wk_g  = (const float*)d_in[4];
  const float* wv_w  = (const float*)d_in[5];
  const float* wv_g  = (const float*)d_in[6];
  const float* wo_w  = (const float*)d_in[7];
  const float* wo_b  = (const float*)d_in[8];
  const float* gamma = (const float*)d_in[9];
  const float* rho   = (const float*)d_in[10];
  float* out = (float*)d_out;

  // workspace layout:
  unsigned* xq8  = (unsigned*)d_ws;                          // 4096*256 u32 (4MB)
  unsigned* wq8  = xq8 + (size_t)MT * KW8;                   // 3*1024*256 u32 (3MB)
  unsigned* qqhm = wq8 + 3ull * NC * KW8;                    // 64*1024*32 u32 (8MB)
  unsigned* kqhm = qqhm + (size_t)NB * NH * NT * 32;         // 8MB
  unsigned short* vhdm = (unsigned short*)(kqhm + (size_t)NB * NH * NT * 32);  // 8MB
  unsigned short* atth = vhdm + (size_t)NB * NH * 64 * NT;   // 4096*1024 f16 (8MB)
  unsigned short* woh  = atth + (size_t)MT * NC;             // 1024*1024 f16 (2MB)

  // 1. tanh + u8 quantize; wo -> f16
  k_tanhq8<<<(MT * NC / 8) / 256, 256, 0, stream>>>(x, xq8, MT * NC / 8);
  k_tanhq8<<<(NC * NC / 8) / 256, 256, 0, stream>>>(wq_w, wq8, NC * NC / 8);
  k_tanhq8<<<(NC * NC / 8) / 256, 256, 0, stream>>>(wk_w, wq8 + (size_t)NC * KW8, NC * NC / 8);
  k_tanhq8<<<(NC * NC / 8) / 256, 256, 0, stream>>>(wv_w, wq8 + 2ull * NC * KW8, NC * NC / 8);
  k_cvt16<<<(NC * NC / 8) / 256, 256, 0, stream>>>(wo_w, woh, NC * NC / 8);

  // 2. q/k/v projections via u8 SAD, emitting attention-ready layouts
  k_sadproj8<<<dim3(NC / 128, MT / 128, 3), 256, 0, stream>>>(xq8, wq8, wq_g, wk_g, wv_g,
                                                              qqhm, kqhm, vhdm);

  // 3. fused Student-t attention (u16 SAD dist + f16 MFMA PV), emits f16 att
  k_attn2<<<dim3(NT / 64, NH, NB), 256, 0, stream>>>(qqhm, kqhm, vhdm, gamma, rho, atth);

  // 4. output projection via f16 MFMA GEMM
  k_gemm16<<<dim3(NC / 128, MT / 128, 1), 256, 0, stream>>>(atth, woh, wo_b, out);
}